// Round 1
// baseline (681.246 us; speedup 1.0000x reference)
//
#include <hip/hip_runtime.h>
#include <math.h>

#define N_PROP 1000
#define NUM_CLASSES 81
#define NFG 80
#define SCORE_THRESH 0.05f
#define NMS_THRESH 0.5f
#define DET_PER_IMG 100
#define KEPT_CAP 20000
// log(1000/16)
#define BBOX_XFORM_CLIP 4.135166556742356f

// ---------------- Kernel 1: softmax + decode + score-filter ----------------
// grid = N_PROP blocks, 128 threads (2 waves). Each block: one proposal.
__global__ __launch_bounds__(128) void k_score_decode(
    const float* __restrict__ logits,   // [N_PROP, 81]
    const float* __restrict__ deltas,   // [N_PROP, 324]
    const float* __restrict__ pboxes,   // [N_PROP, 4]
    const int* __restrict__ ih, const int* __restrict__ iw,
    int* __restrict__ counts,           // [NFG] per-class candidate counts
    float* __restrict__ cand)           // [NFG][N_PROP][6]
{
    const int n = blockIdx.x;
    const int t = threadIdx.x;
    __shared__ float redm[2];
    __shared__ float reds[2];

    float l = (t < NUM_CLASSES) ? logits[n * NUM_CLASSES + t] : -INFINITY;

    // max over 81 (wave64 shuffle reduce, then combine 2 waves)
    float m = l;
    #pragma unroll
    for (int o = 32; o > 0; o >>= 1) m = fmaxf(m, __shfl_xor(m, o));
    const int wave = t >> 6;
    if ((t & 63) == 0) redm[wave] = m;
    __syncthreads();
    m = fmaxf(redm[0], redm[1]);

    float e = (t < NUM_CLASSES) ? expf(l - m) : 0.0f;
    float s = e;
    #pragma unroll
    for (int o = 32; o > 0; o >>= 1) s += __shfl_xor(s, o);
    if ((t & 63) == 0) reds[wave] = s;
    __syncthreads();
    s = reds[0] + reds[1];

    if (t >= 1 && t < NUM_CLASSES) {
        const float prob = e / s;
        if (prob > SCORE_THRESH) {
            // decode class t for proposal n (maskrcnn BoxCoder, TO_REMOVE=1)
            const float x1b = pboxes[n * 4 + 0];
            const float y1b = pboxes[n * 4 + 1];
            const float x2b = pboxes[n * 4 + 2];
            const float y2b = pboxes[n * 4 + 3];
            const float w  = x2b - x1b + 1.0f;
            const float h  = y2b - y1b + 1.0f;
            const float cx = x1b + 0.5f * w;
            const float cy = y1b + 0.5f * h;
            const float* d = deltas + (size_t)n * (NUM_CLASSES * 4) + t * 4;
            const float dx = d[0] / 10.0f;
            const float dy = d[1] / 10.0f;
            const float dw = fminf(d[2] / 5.0f, BBOX_XFORM_CLIP);
            const float dh = fminf(d[3] / 5.0f, BBOX_XFORM_CLIP);
            const float pcx = dx * w + cx;
            const float pcy = dy * h + cy;
            const float pw  = expf(dw) * w;
            const float ph  = expf(dh) * h;
            float X1 = pcx - 0.5f * pw;
            float Y1 = pcy - 0.5f * ph;
            float X2 = pcx + 0.5f * pw - 1.0f;
            float Y2 = pcy + 0.5f * ph - 1.0f;
            const float W = (float)iw[0] - 1.0f;
            const float H = (float)ih[0] - 1.0f;
            X1 = fminf(fmaxf(X1, 0.0f), W);
            Y1 = fminf(fmaxf(Y1, 0.0f), H);
            X2 = fminf(fmaxf(X2, 0.0f), W);
            Y2 = fminf(fmaxf(Y2, 0.0f), H);

            const int c = t - 1;                 // fg class 0..79
            const int pos = atomicAdd(&counts[c], 1);
            if (pos < N_PROP) {
                float* e6 = cand + ((size_t)c * N_PROP + pos) * 6;
                e6[0] = prob;
                e6[1] = X1; e6[2] = Y1; e6[3] = X2; e6[4] = Y2;
                e6[5] = (float)n;                // for stable-sort tie-break
            }
        }
    }
}

// ---------------- Kernel 2: per-class sort + greedy NMS ----------------
// grid = NFG blocks, 256 threads. One class per block.
__global__ __launch_bounds__(256) void k_nms(
    const int* __restrict__ counts,
    const float* __restrict__ cand,
    int* __restrict__ totalCount,       // single int
    float* __restrict__ kept)           // [KEPT_CAP][6]
{
    const int c = blockIdx.x;
    const int tid = threadIdx.x;
    int M = counts[c];
    if (M > N_PROP) M = N_PROP;

    __shared__ float ss[N_PROP];        // unsorted scores
    __shared__ int   si[N_PROP];        // proposal indices
    __shared__ float sb[N_PROP * 4];    // unsorted boxes
    __shared__ float os[N_PROP];        // sorted scores
    __shared__ float ob[N_PROP * 4];    // sorted boxes
    __shared__ int   ok[N_PROP];        // kept flags

    const float* base = cand + (size_t)c * N_PROP * 6;
    for (int i = tid; i < M; i += 256) {
        const float* e6 = base + (size_t)i * 6;
        ss[i] = e6[0];
        sb[i * 4 + 0] = e6[1];
        sb[i * 4 + 1] = e6[2];
        sb[i * 4 + 2] = e6[3];
        sb[i * 4 + 3] = e6[4];
        si[i] = (int)e6[5];
    }
    __syncthreads();

    // rank sort: (score desc, prop_idx asc) — matches stable argsort(-s)
    for (int i = tid; i < M; i += 256) {
        const float s0 = ss[i];
        const int   i0 = si[i];
        int r = 0;
        for (int j = 0; j < M; ++j) {
            const float sj = ss[j];
            r += (sj > s0) || (sj == s0 && si[j] < i0);
        }
        os[r] = s0;
        ob[r * 4 + 0] = sb[i * 4 + 0];
        ob[r * 4 + 1] = sb[i * 4 + 1];
        ob[r * 4 + 2] = sb[i * 4 + 2];
        ob[r * 4 + 3] = sb[i * 4 + 3];
        ok[r] = 1;
    }
    __syncthreads();

    // greedy NMS: sequential over i, parallel suppression of j > i
    for (int i = 0; i < M; ++i) {
        if (ok[i]) {
            const float ax1 = ob[i * 4 + 0], ay1 = ob[i * 4 + 1];
            const float ax2 = ob[i * 4 + 2], ay2 = ob[i * 4 + 3];
            const float aarea = (ax2 - ax1 + 1.0f) * (ay2 - ay1 + 1.0f);
            for (int j = i + 1 + tid; j < M; j += 256) {
                const float bx1 = ob[j * 4 + 0], by1 = ob[j * 4 + 1];
                const float bx2 = ob[j * 4 + 2], by2 = ob[j * 4 + 3];
                const float barea = (bx2 - bx1 + 1.0f) * (by2 - by1 + 1.0f);
                const float ix1 = fmaxf(ax1, bx1), iy1 = fmaxf(ay1, by1);
                const float ix2 = fminf(ax2, bx2), iy2 = fminf(ay2, by2);
                const float iw_ = fmaxf(ix2 - ix1 + 1.0f, 0.0f);
                const float ih_ = fmaxf(iy2 - iy1 + 1.0f, 0.0f);
                const float inter = iw_ * ih_;
                const float iou = inter / (aarea + barea - inter);
                if (iou > NMS_THRESH) ok[j] = 0;
            }
        }
        __syncthreads();
    }

    // append survivors to global kept list
    for (int i = tid; i < M; i += 256) {
        if (ok[i]) {
            const int pos = atomicAdd(totalCount, 1);
            if (pos < KEPT_CAP) {
                float* e6 = kept + (size_t)pos * 6;
                e6[0] = os[i];
                e6[1] = ob[i * 4 + 0];
                e6[2] = ob[i * 4 + 1];
                e6[3] = ob[i * 4 + 2];
                e6[4] = ob[i * 4 + 3];
                e6[5] = (float)(c * N_PROP + i);   // flat key (lax.top_k tie order)
            }
        }
    }
}

// ---------------- Kernel 3: global top-100 by rank ----------------
// fixed grid covering KEPT_CAP; threads with i >= K exit.
__global__ __launch_bounds__(256) void k_topk(
    const int* __restrict__ totalCount,
    const float* __restrict__ kept,
    float* __restrict__ out)            // [100] scores | [100*4] boxes | [100] labels
{
    int K = *totalCount;
    if (K > KEPT_CAP) K = KEPT_CAP;
    const int i = blockIdx.x * 256 + threadIdx.x;
    if (i >= K) return;

    const float s0 = kept[(size_t)i * 6 + 0];
    const float k0 = kept[(size_t)i * 6 + 5];
    int r = 0;
    for (int j = 0; j < K; ++j) {
        const float sj = kept[(size_t)j * 6 + 0];
        const float kj = kept[(size_t)j * 6 + 5];
        r += (sj > s0) || (sj == s0 && kj < k0);
    }
    if (r < DET_PER_IMG) {
        out[r] = s0;
        out[DET_PER_IMG + r * 4 + 0] = kept[(size_t)i * 6 + 1];
        out[DET_PER_IMG + r * 4 + 1] = kept[(size_t)i * 6 + 2];
        out[DET_PER_IMG + r * 4 + 2] = kept[(size_t)i * 6 + 3];
        out[DET_PER_IMG + r * 4 + 3] = kept[(size_t)i * 6 + 4];
        const int key = (int)k0;
        out[DET_PER_IMG * 5 + r] = (float)(key / 1000 + 1);   // label
    }
}

extern "C" void kernel_launch(void* const* d_in, const int* in_sizes, int n_in,
                              void* d_out, int out_size, void* d_ws, size_t ws_size,
                              hipStream_t stream) {
    const float* logits = (const float*)d_in[0];
    const float* deltas = (const float*)d_in[1];
    const float* pboxes = (const float*)d_in[2];
    const int*   ih     = (const int*)d_in[3];
    const int*   iw     = (const int*)d_in[4];
    float* out = (float*)d_out;

    // workspace layout
    int*   counts     = (int*)d_ws;                      // [0..79] counts, [80] total
    int*   totalCount = counts + 80;
    float* cand = (float*)((char*)d_ws + 512);           // 80*1000*6 floats
    float* kept = cand + (size_t)NFG * N_PROP * 6;       // KEPT_CAP*6 floats

    hipMemsetAsync(d_ws, 0, 512, stream);
    hipMemsetAsync(d_out, 0, (size_t)out_size * sizeof(float), stream);

    k_score_decode<<<N_PROP, 128, 0, stream>>>(logits, deltas, pboxes, ih, iw, counts, cand);
    k_nms<<<NFG, 256, 0, stream>>>(counts, cand, totalCount, kept);
    k_topk<<<(KEPT_CAP + 255) / 256, 256, 0, stream>>>(totalCount, kept, out);
}

// Round 2
// 163.995 us; speedup vs baseline: 4.1541x; 4.1541x over previous
//
#include <hip/hip_runtime.h>
#include <math.h>

#define N_PROP 1000
#define NUM_CLASSES 81
#define NFG 80
#define SCORE_THRESH 0.05f
#define NMS_THRESH 0.5f
#define DET_PER_IMG 100
#define PER_CLASS_CAP 100
#define KEPT_CAP (NFG * PER_CLASS_CAP)   /* 8000 */
// log(1000/16)
#define BBOX_XFORM_CLIP 4.135166556742356f

// ---------------- Kernel 1: softmax + decode + score-filter ----------------
// grid = N_PROP blocks, 128 threads (2 waves). Each block: one proposal.
__global__ __launch_bounds__(128) void k_score_decode(
    const float* __restrict__ logits,   // [N_PROP, 81]
    const float* __restrict__ deltas,   // [N_PROP, 324]
    const float* __restrict__ pboxes,   // [N_PROP, 4]
    const int* __restrict__ ih, const int* __restrict__ iw,
    int* __restrict__ counts,           // [NFG] per-class candidate counts
    float* __restrict__ cand)           // [NFG][N_PROP][6]
{
    const int n = blockIdx.x;
    const int t = threadIdx.x;
    __shared__ float redm[2];
    __shared__ float reds[2];

    float l = (t < NUM_CLASSES) ? logits[n * NUM_CLASSES + t] : -INFINITY;

    float m = l;
    #pragma unroll
    for (int o = 32; o > 0; o >>= 1) m = fmaxf(m, __shfl_xor(m, o));
    const int wave = t >> 6;
    if ((t & 63) == 0) redm[wave] = m;
    __syncthreads();
    m = fmaxf(redm[0], redm[1]);

    float e = (t < NUM_CLASSES) ? expf(l - m) : 0.0f;
    float s = e;
    #pragma unroll
    for (int o = 32; o > 0; o >>= 1) s += __shfl_xor(s, o);
    if ((t & 63) == 0) reds[wave] = s;
    __syncthreads();
    s = reds[0] + reds[1];

    if (t >= 1 && t < NUM_CLASSES) {
        const float prob = e / s;
        if (prob > SCORE_THRESH) {
            const float x1b = pboxes[n * 4 + 0];
            const float y1b = pboxes[n * 4 + 1];
            const float x2b = pboxes[n * 4 + 2];
            const float y2b = pboxes[n * 4 + 3];
            const float w  = x2b - x1b + 1.0f;
            const float h  = y2b - y1b + 1.0f;
            const float cx = x1b + 0.5f * w;
            const float cy = y1b + 0.5f * h;
            const float* d = deltas + (size_t)n * (NUM_CLASSES * 4) + t * 4;
            const float dx = d[0] / 10.0f;
            const float dy = d[1] / 10.0f;
            const float dw = fminf(d[2] / 5.0f, BBOX_XFORM_CLIP);
            const float dh = fminf(d[3] / 5.0f, BBOX_XFORM_CLIP);
            const float pcx = dx * w + cx;
            const float pcy = dy * h + cy;
            const float pw  = expf(dw) * w;
            const float ph  = expf(dh) * h;
            float X1 = pcx - 0.5f * pw;
            float Y1 = pcy - 0.5f * ph;
            float X2 = pcx + 0.5f * pw - 1.0f;
            float Y2 = pcy + 0.5f * ph - 1.0f;
            const float W = (float)iw[0] - 1.0f;
            const float H = (float)ih[0] - 1.0f;
            X1 = fminf(fmaxf(X1, 0.0f), W);
            Y1 = fminf(fmaxf(Y1, 0.0f), H);
            X2 = fminf(fmaxf(X2, 0.0f), W);
            Y2 = fminf(fmaxf(Y2, 0.0f), H);

            const int c = t - 1;
            const int pos = atomicAdd(&counts[c], 1);
            if (pos < N_PROP) {
                float* e6 = cand + ((size_t)c * N_PROP + pos) * 6;
                e6[0] = prob;
                e6[1] = X1; e6[2] = Y1; e6[3] = X2; e6[4] = Y2;
                e6[5] = (float)n;
            }
        }
    }
}

// ---------------- Kernel 2: per-class sort + greedy NMS ----------------
// grid = NFG blocks, 256 threads. One class per block.
// Appends at most PER_CLASS_CAP survivors per class (the 101st per-class
// survivor can never reach the global top-100: 100 same-class survivors
// rank strictly above it).
__global__ __launch_bounds__(256) void k_nms(
    const int* __restrict__ counts,
    const float* __restrict__ cand,
    int* __restrict__ totalCount,
    float* __restrict__ keptScore,      // [KEPT_CAP]
    unsigned* __restrict__ keptKey,     // [KEPT_CAP] flat key c*1000+pos
    float4* __restrict__ keptBox)       // [KEPT_CAP]
{
    const int c = blockIdx.x;
    const int tid = threadIdx.x;
    int M = counts[c];
    if (M > N_PROP) M = N_PROP;

    __shared__ float ss[N_PROP];
    __shared__ int   si[N_PROP];
    __shared__ float sb[N_PROP * 4];
    __shared__ float os[N_PROP];
    __shared__ float ob[N_PROP * 4];
    __shared__ int   ok[N_PROP];

    const float* base = cand + (size_t)c * N_PROP * 6;
    for (int i = tid; i < M; i += 256) {
        const float* e6 = base + (size_t)i * 6;
        ss[i] = e6[0];
        sb[i * 4 + 0] = e6[1];
        sb[i * 4 + 1] = e6[2];
        sb[i * 4 + 2] = e6[3];
        sb[i * 4 + 3] = e6[4];
        si[i] = (int)e6[5];
    }
    __syncthreads();

    // rank sort: (score desc, prop_idx asc) — matches stable argsort(-s)
    for (int i = tid; i < M; i += 256) {
        const float s0 = ss[i];
        const int   i0 = si[i];
        int r = 0;
        for (int j = 0; j < M; ++j) {
            const float sj = ss[j];
            r += (sj > s0) || (sj == s0 && si[j] < i0);
        }
        os[r] = s0;
        ob[r * 4 + 0] = sb[i * 4 + 0];
        ob[r * 4 + 1] = sb[i * 4 + 1];
        ob[r * 4 + 2] = sb[i * 4 + 2];
        ob[r * 4 + 3] = sb[i * 4 + 3];
        ok[r] = 1;
    }
    __syncthreads();

    // greedy NMS: sequential over i, parallel suppression of j > i
    for (int i = 0; i < M; ++i) {
        if (ok[i]) {
            const float ax1 = ob[i * 4 + 0], ay1 = ob[i * 4 + 1];
            const float ax2 = ob[i * 4 + 2], ay2 = ob[i * 4 + 3];
            const float aarea = (ax2 - ax1 + 1.0f) * (ay2 - ay1 + 1.0f);
            for (int j = i + 1 + tid; j < M; j += 256) {
                const float bx1 = ob[j * 4 + 0], by1 = ob[j * 4 + 1];
                const float bx2 = ob[j * 4 + 2], by2 = ob[j * 4 + 3];
                const float barea = (bx2 - bx1 + 1.0f) * (by2 - by1 + 1.0f);
                const float ix1 = fmaxf(ax1, bx1), iy1 = fmaxf(ay1, by1);
                const float ix2 = fminf(ax2, bx2), iy2 = fminf(ay2, by2);
                const float iw_ = fmaxf(ix2 - ix1 + 1.0f, 0.0f);
                const float ih_ = fmaxf(iy2 - iy1 + 1.0f, 0.0f);
                const float inter = iw_ * ih_;
                const float iou = inter / (aarea + barea - inter);
                if (iou > NMS_THRESH) ok[j] = 0;
            }
        }
        __syncthreads();
    }

    // append survivors (per-class survivor rank < PER_CLASS_CAP only)
    for (int i = tid; i < M; i += 256) {
        if (ok[i]) {
            int sr = 0;
            for (int j = 0; j < i; ++j) sr += ok[j];
            if (sr < PER_CLASS_CAP) {
                const int pos = atomicAdd(totalCount, 1);
                if (pos < KEPT_CAP) {
                    keptScore[pos] = os[i];
                    keptKey[pos]   = (unsigned)(c * N_PROP + i);
                    keptBox[pos]   = make_float4(ob[i * 4 + 0], ob[i * 4 + 1],
                                                 ob[i * 4 + 2], ob[i * 4 + 3]);
                }
            }
        }
    }
}

// ---------------- Kernel 3: global top-100 via LDS rank ----------------
// Each block loads ALL K packed keys into LDS (K <= 8000, 64000 B), then
// ranks 128 elements with 2 threads/element (each scans half, combine via
// shfl). packed = (score_bits << 32) | ~flatkey  ==> descending (score,
// then ascending flatkey) == lax.top_k tie order.
__global__ __launch_bounds__(256) void k_topk(
    const int* __restrict__ totalCount,
    const float* __restrict__ keptScore,
    const unsigned* __restrict__ keptKey,
    const float4* __restrict__ keptBox,
    float* __restrict__ out)            // [100] scores | [400] boxes | [100] labels
{
    __shared__ unsigned long long pk[KEPT_CAP];
    int K = *totalCount;
    if (K > KEPT_CAP) K = KEPT_CAP;
    const int blockStart = blockIdx.x * 128;
    if (blockStart >= K) return;

    for (int j = threadIdx.x; j < K; j += 256) {
        pk[j] = ((unsigned long long)__float_as_uint(keptScore[j]) << 32)
              | (unsigned)(~keptKey[j]);
    }
    __syncthreads();

    const int e    = blockStart + (threadIdx.x >> 1);
    const int half = threadIdx.x & 1;
    const bool active = (e < K);
    const unsigned long long mykey = active ? pk[e] : 0ull;

    const int mid = K >> 1;
    const int lo = half ? mid : 0;
    const int hi = half ? K   : mid;
    int r = 0;
    for (int j = lo; j < hi; ++j) r += (pk[j] > mykey) ? 1 : 0;
    r += __shfl_xor(r, 1);

    if (active && half == 0 && r < DET_PER_IMG) {
        out[r] = keptScore[e];
        const float4 b = keptBox[e];
        out[DET_PER_IMG + r * 4 + 0] = b.x;
        out[DET_PER_IMG + r * 4 + 1] = b.y;
        out[DET_PER_IMG + r * 4 + 2] = b.z;
        out[DET_PER_IMG + r * 4 + 3] = b.w;
        const unsigned key = keptKey[e];
        out[DET_PER_IMG * 5 + r] = (float)(key / N_PROP + 1);
    }
}

extern "C" void kernel_launch(void* const* d_in, const int* in_sizes, int n_in,
                              void* d_out, int out_size, void* d_ws, size_t ws_size,
                              hipStream_t stream) {
    const float* logits = (const float*)d_in[0];
    const float* deltas = (const float*)d_in[1];
    const float* pboxes = (const float*)d_in[2];
    const int*   ih     = (const int*)d_in[3];
    const int*   iw     = (const int*)d_in[4];
    float* out = (float*)d_out;

    // workspace layout
    int*   counts     = (int*)d_ws;                      // [0..79], [80]=total
    int*   totalCount = counts + 80;
    char*  p = (char*)d_ws + 512;
    float* cand = (float*)p;                 p += (size_t)NFG * N_PROP * 6 * 4;
    float* keptScore = (float*)p;            p += (size_t)KEPT_CAP * 4;
    unsigned* keptKey = (unsigned*)p;        p += (size_t)KEPT_CAP * 4;
    float4* keptBox = (float4*)p;            p += (size_t)KEPT_CAP * 16;

    hipMemsetAsync(d_ws, 0, 512, stream);
    hipMemsetAsync(d_out, 0, (size_t)out_size * sizeof(float), stream);

    k_score_decode<<<N_PROP, 128, 0, stream>>>(logits, deltas, pboxes, ih, iw, counts, cand);
    k_nms<<<NFG, 256, 0, stream>>>(counts, cand, totalCount, keptScore, keptKey, keptBox);
    k_topk<<<(KEPT_CAP + 127) / 128, 256, 0, stream>>>(totalCount, keptScore, keptKey, keptBox, out);
}

// Round 3
// 77.668 us; speedup vs baseline: 8.7713x; 2.1115x over previous
//
#include <hip/hip_runtime.h>
#include <math.h>

#define N_PROP 1000
#define NUM_CLASSES 81
#define NFG 80
#define SCORE_THRESH 0.05f
#define NMS_THRESH 0.5f
#define DET_PER_IMG 100
#define PER_CLASS_CAP 100
#define KEPT_CAP (NFG * PER_CLASS_CAP)   /* 8000 */
// log(1000/16)
#define BBOX_XFORM_CLIP 4.135166556742356f

// ---------------- Kernel 1: softmax + decode + score-filter ----------------
__global__ __launch_bounds__(128) void k_score_decode(
    const float* __restrict__ logits,   // [N_PROP, 81]
    const float* __restrict__ deltas,   // [N_PROP, 324]
    const float* __restrict__ pboxes,   // [N_PROP, 4]
    const int* __restrict__ ih, const int* __restrict__ iw,
    int* __restrict__ counts,           // [NFG]
    float* __restrict__ cand)           // [NFG][N_PROP][6]
{
    const int n = blockIdx.x;
    const int t = threadIdx.x;
    __shared__ float redm[2];
    __shared__ float reds[2];

    float l = (t < NUM_CLASSES) ? logits[n * NUM_CLASSES + t] : -INFINITY;

    float m = l;
    #pragma unroll
    for (int o = 32; o > 0; o >>= 1) m = fmaxf(m, __shfl_xor(m, o));
    const int wave = t >> 6;
    if ((t & 63) == 0) redm[wave] = m;
    __syncthreads();
    m = fmaxf(redm[0], redm[1]);

    float e = (t < NUM_CLASSES) ? expf(l - m) : 0.0f;
    float s = e;
    #pragma unroll
    for (int o = 32; o > 0; o >>= 1) s += __shfl_xor(s, o);
    if ((t & 63) == 0) reds[wave] = s;
    __syncthreads();
    s = reds[0] + reds[1];

    if (t >= 1 && t < NUM_CLASSES) {
        const float prob = e / s;
        if (prob > SCORE_THRESH) {
            const float x1b = pboxes[n * 4 + 0];
            const float y1b = pboxes[n * 4 + 1];
            const float x2b = pboxes[n * 4 + 2];
            const float y2b = pboxes[n * 4 + 3];
            const float w  = x2b - x1b + 1.0f;
            const float h  = y2b - y1b + 1.0f;
            const float cx = x1b + 0.5f * w;
            const float cy = y1b + 0.5f * h;
            const float* d = deltas + (size_t)n * (NUM_CLASSES * 4) + t * 4;
            const float dx = d[0] / 10.0f;
            const float dy = d[1] / 10.0f;
            const float dw = fminf(d[2] / 5.0f, BBOX_XFORM_CLIP);
            const float dh = fminf(d[3] / 5.0f, BBOX_XFORM_CLIP);
            const float pcx = dx * w + cx;
            const float pcy = dy * h + cy;
            const float pw  = expf(dw) * w;
            const float ph  = expf(dh) * h;
            float X1 = pcx - 0.5f * pw;
            float Y1 = pcy - 0.5f * ph;
            float X2 = pcx + 0.5f * pw - 1.0f;
            float Y2 = pcy + 0.5f * ph - 1.0f;
            const float W = (float)iw[0] - 1.0f;
            const float H = (float)ih[0] - 1.0f;
            X1 = fminf(fmaxf(X1, 0.0f), W);
            Y1 = fminf(fmaxf(Y1, 0.0f), H);
            X2 = fminf(fmaxf(X2, 0.0f), W);
            Y2 = fminf(fmaxf(Y2, 0.0f), H);

            const int c = t - 1;
            const int pos = atomicAdd(&counts[c], 1);
            if (pos < N_PROP) {
                float* e6 = cand + ((size_t)c * N_PROP + pos) * 6;
                e6[0] = prob;
                e6[1] = X1; e6[2] = Y1; e6[3] = X2; e6[4] = Y2;
                e6[5] = (float)n;
            }
        }
    }
}

// ---------------- Kernel 2: per-class sort + greedy NMS ----------------
__global__ __launch_bounds__(256) void k_nms(
    const int* __restrict__ counts,
    const float* __restrict__ cand,
    int* __restrict__ totalCount,
    float* __restrict__ keptScore,      // [KEPT_CAP]
    unsigned* __restrict__ keptKey,     // [KEPT_CAP]
    float4* __restrict__ keptBox)       // [KEPT_CAP]
{
    const int c = blockIdx.x;
    const int tid = threadIdx.x;
    int M = counts[c];
    if (M > N_PROP) M = N_PROP;

    __shared__ float ss[N_PROP];
    __shared__ int   si[N_PROP];
    __shared__ float sb[N_PROP * 4];
    __shared__ float os[N_PROP];
    __shared__ float ob[N_PROP * 4];
    __shared__ int   ok[N_PROP];

    const float* base = cand + (size_t)c * N_PROP * 6;
    for (int i = tid; i < M; i += 256) {
        const float* e6 = base + (size_t)i * 6;
        ss[i] = e6[0];
        sb[i * 4 + 0] = e6[1];
        sb[i * 4 + 1] = e6[2];
        sb[i * 4 + 2] = e6[3];
        sb[i * 4 + 3] = e6[4];
        si[i] = (int)e6[5];
    }
    __syncthreads();

    // rank sort: (score desc, prop_idx asc)
    for (int i = tid; i < M; i += 256) {
        const float s0 = ss[i];
        const int   i0 = si[i];
        int r = 0;
        for (int j = 0; j < M; ++j) {
            const float sj = ss[j];
            r += (sj > s0) || (sj == s0 && si[j] < i0);
        }
        os[r] = s0;
        ob[r * 4 + 0] = sb[i * 4 + 0];
        ob[r * 4 + 1] = sb[i * 4 + 1];
        ob[r * 4 + 2] = sb[i * 4 + 2];
        ob[r * 4 + 3] = sb[i * 4 + 3];
        ok[r] = 1;
    }
    __syncthreads();

    // greedy NMS
    for (int i = 0; i < M; ++i) {
        if (ok[i]) {
            const float ax1 = ob[i * 4 + 0], ay1 = ob[i * 4 + 1];
            const float ax2 = ob[i * 4 + 2], ay2 = ob[i * 4 + 3];
            const float aarea = (ax2 - ax1 + 1.0f) * (ay2 - ay1 + 1.0f);
            for (int j = i + 1 + tid; j < M; j += 256) {
                const float bx1 = ob[j * 4 + 0], by1 = ob[j * 4 + 1];
                const float bx2 = ob[j * 4 + 2], by2 = ob[j * 4 + 3];
                const float barea = (bx2 - bx1 + 1.0f) * (by2 - by1 + 1.0f);
                const float ix1 = fmaxf(ax1, bx1), iy1 = fmaxf(ay1, by1);
                const float ix2 = fminf(ax2, bx2), iy2 = fminf(ay2, by2);
                const float iw_ = fmaxf(ix2 - ix1 + 1.0f, 0.0f);
                const float ih_ = fmaxf(iy2 - iy1 + 1.0f, 0.0f);
                const float inter = iw_ * ih_;
                const float iou = inter / (aarea + barea - inter);
                if (iou > NMS_THRESH) ok[j] = 0;
            }
        }
        __syncthreads();
    }

    // append survivors (per-class survivor rank < PER_CLASS_CAP)
    for (int i = tid; i < M; i += 256) {
        if (ok[i]) {
            int sr = 0;
            for (int j = 0; j < i; ++j) sr += ok[j];
            if (sr < PER_CLASS_CAP) {
                const int pos = atomicAdd(totalCount, 1);
                if (pos < KEPT_CAP) {
                    keptScore[pos] = os[i];
                    keptKey[pos]   = (unsigned)(c * N_PROP + i);
                    keptBox[pos]   = make_float4(ob[i * 4 + 0], ob[i * 4 + 1],
                                                 ob[i * 4 + 2], ob[i * 4 + 3]);
                }
            }
        }
    }
}

// ---------------- Kernel 3: global top-100 via LDS rank ----------------
// 64 elements/block, 4 threads per element, 8x-unrolled LDS scan for ILP.
__global__ __launch_bounds__(256) void k_topk(
    const int* __restrict__ totalCount,
    const float* __restrict__ keptScore,
    const unsigned* __restrict__ keptKey,
    const float4* __restrict__ keptBox,
    float* __restrict__ out)            // [100] scores | [400] boxes | [100] labels
{
    __shared__ unsigned long long pk[KEPT_CAP];
    int K = *totalCount;
    if (K > KEPT_CAP) K = KEPT_CAP;
    const int blockStart = blockIdx.x * 64;
    if (blockStart >= K) return;

    for (int j = threadIdx.x; j < K; j += 256) {
        pk[j] = ((unsigned long long)__float_as_uint(keptScore[j]) << 32)
              | (unsigned)(~keptKey[j]);
    }
    __syncthreads();

    const int e    = blockStart + (threadIdx.x >> 2);
    const int part = threadIdx.x & 3;
    const bool active = (e < K);
    const unsigned long long mykey = active ? pk[e] : 0ull;

    const int lo = (K * part) >> 2;
    const int hi = (K * (part + 1)) >> 2;
    int r = 0;
    int j = lo;
    for (; j + 8 <= hi; j += 8) {
        const unsigned long long k0 = pk[j + 0];
        const unsigned long long k1 = pk[j + 1];
        const unsigned long long k2 = pk[j + 2];
        const unsigned long long k3 = pk[j + 3];
        const unsigned long long k4 = pk[j + 4];
        const unsigned long long k5 = pk[j + 5];
        const unsigned long long k6 = pk[j + 6];
        const unsigned long long k7 = pk[j + 7];
        r += (int)(k0 > mykey) + (int)(k1 > mykey)
           + (int)(k2 > mykey) + (int)(k3 > mykey)
           + (int)(k4 > mykey) + (int)(k5 > mykey)
           + (int)(k6 > mykey) + (int)(k7 > mykey);
    }
    for (; j < hi; ++j) r += (int)(pk[j] > mykey);

    // combine across the 4 lanes owning this element (lanes 4k..4k+3)
    r += __shfl_xor(r, 1);
    r += __shfl_xor(r, 2);

    if (active && part == 0 && r < DET_PER_IMG) {
        out[r] = keptScore[e];
        const float4 b = keptBox[e];
        out[DET_PER_IMG + r * 4 + 0] = b.x;
        out[DET_PER_IMG + r * 4 + 1] = b.y;
        out[DET_PER_IMG + r * 4 + 2] = b.z;
        out[DET_PER_IMG + r * 4 + 3] = b.w;
        const unsigned key = keptKey[e];
        out[DET_PER_IMG * 5 + r] = (float)(key / N_PROP + 1);
    }
}

extern "C" void kernel_launch(void* const* d_in, const int* in_sizes, int n_in,
                              void* d_out, int out_size, void* d_ws, size_t ws_size,
                              hipStream_t stream) {
    const float* logits = (const float*)d_in[0];
    const float* deltas = (const float*)d_in[1];
    const float* pboxes = (const float*)d_in[2];
    const int*   ih     = (const int*)d_in[3];
    const int*   iw     = (const int*)d_in[4];
    float* out = (float*)d_out;

    int*   counts     = (int*)d_ws;                      // [0..79], [80]=total
    int*   totalCount = counts + 80;
    char*  p = (char*)d_ws + 512;
    float* cand = (float*)p;                 p += (size_t)NFG * N_PROP * 6 * 4;
    float* keptScore = (float*)p;            p += (size_t)KEPT_CAP * 4;
    unsigned* keptKey = (unsigned*)p;        p += (size_t)KEPT_CAP * 4;
    float4* keptBox = (float4*)p;            p += (size_t)KEPT_CAP * 16;

    hipMemsetAsync(d_ws, 0, 512, stream);
    hipMemsetAsync(d_out, 0, (size_t)out_size * sizeof(float), stream);

    k_score_decode<<<N_PROP, 128, 0, stream>>>(logits, deltas, pboxes, ih, iw, counts, cand);
    k_nms<<<NFG, 256, 0, stream>>>(counts, cand, totalCount, keptScore, keptKey, keptBox);
    k_topk<<<(KEPT_CAP + 63) / 64, 256, 0, stream>>>(totalCount, keptScore, keptKey, keptBox, out);
}